// Round 1
// baseline (6873.621 us; speedup 1.0000x reference)
//
#include <hip/hip_runtime.h>
#include <cstddef>
#include <cstdint>

// SDCN GNN: 5 × (dense GEMM + sparse A@· ) + softmax.
// Key identities used:
//   A@(F@W) = (A@F)@W  → layer-3 SpMM runs on the 500-wide input, not 2000-wide.
//   Layer-3 GEMM (500->2000) fused with mix(tra3) and layer-4 GEMM (2000->10):
//   h3 (50000x2000, 400MB) is never materialized.
// SpMM uses on-device CSR (built per launch) — no float atomics.

constexpr int D_IN = 512;   // input width
constexpr int D1   = 500;   // enc1 width (= wide SpMM width)
constexpr int D2   = 500;   // enc2 width
constexpr int D3   = 2000;  // enc3 width
constexpr int DC   = 10;    // z / cluster width

// ---------------------------------------------------------------- CSR build
__global__ void zero_i32(int* __restrict__ p, int n) {
    int i = blockIdx.x * 256 + threadIdx.x;
    if (i < n) p[i] = 0;
}

__global__ void count_edges(const int* __restrict__ row, int E, int* __restrict__ cnt) {
    int e = blockIdx.x * 256 + threadIdx.x;
    if (e < E) atomicAdd(&cnt[row[e]], 1);
}

// single-block exclusive scan over cnt[0..Nr) -> rp (and a copy into cur)
__global__ __launch_bounds__(1024) void scan_rowptr(const int* __restrict__ cnt, int Nr,
                                                    int* __restrict__ rp, int* __restrict__ cur) {
    __shared__ int sb[1024];
    const int t = threadIdx.x;
    int carry = 0;
    for (int base = 0; base < Nr; base += 1024) {
        int idx = base + t;
        int c = (idx < Nr) ? cnt[idx] : 0;
        sb[t] = c;
        __syncthreads();
        for (int off = 1; off < 1024; off <<= 1) {
            int add = (t >= off) ? sb[t - off] : 0;
            __syncthreads();
            sb[t] += add;
            __syncthreads();
        }
        if (idx < Nr) { int ex = carry + sb[t] - c; rp[idx] = ex; cur[idx] = ex; }
        carry += sb[1023];
        __syncthreads();
    }
    if (t == 0) rp[Nr] = carry;
}

__global__ void scatter_edges(const int* __restrict__ row, const int* __restrict__ col,
                              const float* __restrict__ val, int E,
                              int* __restrict__ cur, int* __restrict__ ci,
                              float* __restrict__ cv) {
    int e = blockIdx.x * 256 + threadIdx.x;
    if (e < E) {
        int r = row[e];
        int p = atomicAdd(&cur[r], 1);
        ci[p] = col[e];
        cv[p] = val[e];
    }
}

// ---------------------------------------------------------------- dense GEMM
// C(MxN) = A(MxK) @ B(KxN), fp32 row-major, 64x64 tile, 4x4 per thread.
constexpr int BM = 64, BN = 64, BK = 16;

__global__ __launch_bounds__(256) void gemm_tiled(const float* __restrict__ A,
                                                  const float* __restrict__ B,
                                                  float* __restrict__ C,
                                                  int M, int K, int Nn) {
    __shared__ float As[BM][BK + 1];
    __shared__ float Bs[BK][BN];
    const int tid = threadIdx.x;
    const int tx = tid & 15, ty = tid >> 4;
    const int rowBase = blockIdx.y * BM, colBase = blockIdx.x * BN;
    float acc[4][4] = {};
    for (int k0 = 0; k0 < K; k0 += BK) {
        for (int e = tid; e < BM * BK; e += 256) {
            int m = e >> 4, k = e & 15;
            int gr = rowBase + m, gk = k0 + k;
            As[m][k] = (gr < M && gk < K) ? A[(size_t)gr * K + gk] : 0.f;
        }
        for (int e = tid; e < BK * BN; e += 256) {
            int k = e >> 6, n = e & 63;
            int gk = k0 + k, gc = colBase + n;
            Bs[k][n] = (gk < K && gc < Nn) ? B[(size_t)gk * Nn + gc] : 0.f;
        }
        __syncthreads();
        for (int k = 0; k < BK; k++) {
            float a[4], b[4];
#pragma unroll
            for (int i = 0; i < 4; i++) a[i] = As[ty * 4 + i][k];
#pragma unroll
            for (int j = 0; j < 4; j++) b[j] = Bs[k][tx * 4 + j];
#pragma unroll
            for (int i = 0; i < 4; i++)
#pragma unroll
                for (int j = 0; j < 4; j++) acc[i][j] += a[i] * b[j];
        }
        __syncthreads();
    }
#pragma unroll
    for (int i = 0; i < 4; i++) {
        int gr = rowBase + ty * 4 + i;
        if (gr >= M) continue;
#pragma unroll
        for (int j = 0; j < 4; j++) {
            int gc = colBase + tx * 4 + j;
            if (gc < Nn) C[(size_t)gr * Nn + gc] = acc[i][j];
        }
    }
}

// ---------------------------------------------------- fused gemm3+mix+gemm4
// t4[i,c] = sum_j (0.5*relu((g3@W3)[i,j]) + 0.5*tra3[i,j]) * W4[j,c]
// 16 rows per block; g3 stripe (16x500) in LDS; J-chunks of 256 cols;
// P chunk (16x256) lives only in LDS; 16x10 accumulator carried in registers.
constexpr int R34 = 16;   // rows per block (50000 % 16 == 0)
constexpr int JB  = 256;  // j-chunk

__global__ __launch_bounds__(256) void gemm34(const float* __restrict__ g3,
                                              const float* __restrict__ tra3,
                                              const float* __restrict__ W3,
                                              const float* __restrict__ W4,
                                              float* __restrict__ t4) {
    __shared__ float gs[R34 * D2];        // 32000 B
    __shared__ float Ps[R34 * JB];        // 16384 B
    __shared__ float red[R34][16][DC];    // 10240 B
    const int t = threadIdx.x;
    const size_t i0 = (size_t)blockIdx.x * R34;

    for (int e = t; e < R34 * D2; e += 256) gs[e] = g3[i0 * D2 + e];

    // phase-1 mapping: 4 rows x 4 cols per thread
    const int j4 = (t & 63) * 4;     // col offset within chunk
    const int rbase = (t >> 6) * 4;  // row group
    // phase-2 mapping: row r2, strided lane l2 over jj
    const int r2 = t >> 4, l2 = t & 15;
    float acc2[DC] = {};

    __syncthreads();
    for (int j0 = 0; j0 < D3; j0 += JB) {
        const int jb = min(JB, D3 - j0);
        float pacc[4][4] = {};
        if (j4 < jb) {
            for (int k = 0; k < D2; k += 4) {
                float ga[4][4], wa[4][4];
#pragma unroll
                for (int i = 0; i < 4; i++)
                    *reinterpret_cast<float4*>(ga[i]) =
                        *reinterpret_cast<const float4*>(&gs[(rbase + i) * D2 + k]);
#pragma unroll
                for (int kk = 0; kk < 4; kk++)
                    *reinterpret_cast<float4*>(wa[kk]) =
                        *reinterpret_cast<const float4*>(&W3[(size_t)(k + kk) * D3 + j0 + j4]);
#pragma unroll
                for (int kk = 0; kk < 4; kk++)
#pragma unroll
                    for (int i = 0; i < 4; i++)
#pragma unroll
                        for (int jj = 0; jj < 4; jj++)
                            pacc[i][jj] += ga[i][kk] * wa[kk][jj];
            }
        }
        __syncthreads();  // previous chunk's phase-2 done with Ps
        if (j4 < jb) {
#pragma unroll
            for (int i = 0; i < 4; i++) {
                float4 o;
                o.x = fmaxf(pacc[i][0], 0.f);
                o.y = fmaxf(pacc[i][1], 0.f);
                o.z = fmaxf(pacc[i][2], 0.f);
                o.w = fmaxf(pacc[i][3], 0.f);
                *reinterpret_cast<float4*>(&Ps[(rbase + i) * JB + j4]) = o;
            }
        }
        __syncthreads();  // Ps visible
        {
            const float* trarow = tra3 + (i0 + r2) * (size_t)D3 + j0;
            for (int jj = l2; jj < jb; jj += 16) {
                float pv = 0.5f * Ps[r2 * JB + jj] + 0.5f * trarow[jj];
                const float* w4r = W4 + (size_t)(j0 + jj) * DC;
#pragma unroll
                for (int c = 0; c < DC; c++) acc2[c] += pv * w4r[c];
            }
        }
    }
    __syncthreads();
#pragma unroll
    for (int c = 0; c < DC; c++) red[r2][l2][c] = acc2[c];
    __syncthreads();
    if (t < R34 * DC) {
        int rr = t / DC, cc = t - rr * DC;
        float s = 0.f;
#pragma unroll
        for (int l = 0; l < 16; l++) s += red[rr][l][cc];
        t4[(i0 + rr) * DC + cc] = s;
    }
}

// ---------------------------------------------------------------- SpMM (CSR)
// wide (width = 500): one block per row, 256 threads, <=2 cols per thread
__global__ __launch_bounds__(256) void spmm_w(const int* __restrict__ rp,
                                              const int* __restrict__ ci,
                                              const float* __restrict__ cv,
                                              const float* __restrict__ m,
                                              float* __restrict__ out,
                                              const float* __restrict__ mix,
                                              int relu) {
    const int i = blockIdx.x, t = threadIdx.x;
    const int c0 = t, c1 = t + 256;  // c1 valid for t < D1-256
    float a0 = 0.f, a1 = 0.f;
    const int pb = rp[i], pe = rp[i + 1];
    for (int p = pb; p < pe; p++) {
        const int col = ci[p];
        const float v = cv[p];
        const float* mr = m + (size_t)col * D1;
        a0 += v * mr[c0];
        if (c1 < D1) a1 += v * mr[c1];
    }
    if (relu) { a0 = fmaxf(a0, 0.f); a1 = fmaxf(a1, 0.f); }
    const size_t o = (size_t)i * D1;
    if (mix) {
        out[o + c0] = 0.5f * a0 + 0.5f * mix[o + c0];
        if (c1 < D1) out[o + c1] = 0.5f * a1 + 0.5f * mix[o + c1];
    } else {
        out[o + c0] = a0;
        if (c1 < D1) out[o + c1] = a1;
    }
}

// narrow (width = 10): 25 rows per block, thread = (row, col)
__global__ __launch_bounds__(256) void spmm_n(const int* __restrict__ rp,
                                              const int* __restrict__ ci,
                                              const float* __restrict__ cv,
                                              const float* __restrict__ m,
                                              float* __restrict__ out,
                                              const float* __restrict__ mix,
                                              int relu, int Nr) {
    const int t = threadIdx.x;
    const int lr = t / DC, c = t - lr * DC;
    if (lr >= 25) return;
    const int i = blockIdx.x * 25 + lr;
    if (i >= Nr) return;
    float a = 0.f;
    const int pb = rp[i], pe = rp[i + 1];
    for (int p = pb; p < pe; p++) a += cv[p] * m[(size_t)ci[p] * DC + c];
    if (relu) a = fmaxf(a, 0.f);
    if (mix) a = 0.5f * a + 0.5f * mix[(size_t)i * DC + c];
    out[(size_t)i * DC + c] = a;
}

// ---------------------------------------------------------------- softmax
__global__ void softmax10(const float* __restrict__ in, float* __restrict__ out, int Nr) {
    int i = blockIdx.x * 256 + threadIdx.x;
    if (i >= Nr) return;
    const float* r = in + (size_t)i * DC;
    float v[DC], mx = r[0];
#pragma unroll
    for (int c = 0; c < DC; c++) { v[c] = r[c]; mx = fmaxf(mx, v[c]); }
    float s = 0.f;
#pragma unroll
    for (int c = 0; c < DC; c++) { v[c] = __expf(v[c] - mx); s += v[c]; }
    float inv = 1.0f / s;
    float* o = out + (size_t)i * DC;
#pragma unroll
    for (int c = 0; c < DC; c++) o[c] = v[c] * inv;
}

// ---------------------------------------------------------------- launcher
extern "C" void kernel_launch(void* const* d_in, const int* in_sizes, int n_in,
                              void* d_out, int out_size, void* d_ws, size_t ws_size,
                              hipStream_t stream) {
    const float* x    = (const float*)d_in[0];
    const float* tra1 = (const float*)d_in[1];
    const float* tra2 = (const float*)d_in[2];
    const float* tra3 = (const float*)d_in[3];
    const float* z    = (const float*)d_in[4];
    const float* ev   = (const float*)d_in[5];
    const int*   erow = (const int*)d_in[6];
    const int*   ecol = (const int*)d_in[7];
    const float* W1   = (const float*)d_in[8];
    const float* W2   = (const float*)d_in[9];
    const float* W3   = (const float*)d_in[10];
    const float* W4   = (const float*)d_in[11];
    const float* W5   = (const float*)d_in[12];

    const int Nr = in_sizes[4] / DC;  // 50000
    const int E  = in_sizes[5];       // 1600000

    // workspace layout (~220 MB total)
    char* ws = (char*)d_ws;
    size_t off = 0;
    auto alloc = [&](size_t bytes) -> char* {
        char* p = ws + off;
        off = (off + bytes + 255) & ~(size_t)255;
        return p;
    };
    float* B0  = (float*)alloc((size_t)Nr * D1 * 4);      // 100 MB ping
    float* B1  = (float*)alloc((size_t)Nr * D1 * 4);      // 100 MB pong
    float* t4  = (float*)alloc((size_t)Nr * DC * 4);
    float* a4  = (float*)alloc((size_t)Nr * DC * 4);
    float* g5  = (float*)alloc((size_t)Nr * DC * 4);
    float* pre = (float*)alloc((size_t)Nr * DC * 4);
    int*   rp  = (int*)alloc((size_t)(Nr + 1) * 4);
    int*   cur = (int*)alloc((size_t)Nr * 4);
    int*   cnt = (int*)alloc((size_t)Nr * 4);
    int*   ci  = (int*)alloc((size_t)E * 4);
    float* cv  = (float*)alloc((size_t)E * 4);

    const int eb = (E + 255) / 256;
    const int nb = (Nr + 255) / 256;

    // CSR build
    zero_i32<<<nb, 256, 0, stream>>>(cnt, Nr);
    count_edges<<<eb, 256, 0, stream>>>(erow, E, cnt);
    scan_rowptr<<<1, 1024, 0, stream>>>(cnt, Nr, rp, cur);
    scatter_edges<<<eb, 256, 0, stream>>>(erow, ecol, ev, E, cur, ci, cv);

    auto gg = [&](int M, int Nn) { return dim3((Nn + BN - 1) / BN, (M + BM - 1) / BM); };

    // L1: h1' = 0.5*relu(A@(x@W1)) + 0.5*tra1
    gemm_tiled<<<gg(Nr, D1), 256, 0, stream>>>(x, W1, B0, Nr, D_IN, D1);
    spmm_w<<<Nr, 256, 0, stream>>>(rp, ci, cv, B0, B1, tra1, 1);
    // L2: h2' = 0.5*relu(A@(h1'@W2)) + 0.5*tra2
    gemm_tiled<<<gg(Nr, D2), 256, 0, stream>>>(B1, W2, B0, Nr, D1, D2);
    spmm_w<<<Nr, 256, 0, stream>>>(rp, ci, cv, B0, B1, tra2, 1);
    // L3 (SpMM first): g3 = A@h2'
    spmm_w<<<Nr, 256, 0, stream>>>(rp, ci, cv, B1, B0, nullptr, 0);
    // L3 GEMM + mix(tra3) + L4 GEMM, fused: t4 = (0.5*relu(g3@W3)+0.5*tra3)@W4
    gemm34<<<Nr / R34, 256, 0, stream>>>(B0, tra3, W3, W4, t4);
    // L4 SpMM: a4 = 0.5*relu(A@t4) + 0.5*z
    spmm_n<<<(Nr + 24) / 25, 256, 0, stream>>>(rp, ci, cv, t4, a4, z, 1, Nr);
    // L5: pre = A@(a4@W5)
    gemm_tiled<<<gg(Nr, DC), 256, 0, stream>>>(a4, W5, g5, Nr, DC, DC);
    spmm_n<<<(Nr + 24) / 25, 256, 0, stream>>>(rp, ci, cv, g5, pre, nullptr, 0, Nr);
    // softmax
    softmax10<<<nb, 256, 0, stream>>>(pre, (float*)d_out, Nr);
}